// Round 15
// baseline (937.672 us; speedup 1.0000x reference)
//
#include <hip/hip_runtime.h>

// LSTM T=256, B=128, D=512, H=512 — round 15: r10 + speculative h-load.
//   r10 protocol verbatim (644us best): publish h -> __syncthreads drain ->
//   tid0 fetch_add on padded per-(grp,t) counter -> consumers spin on counter
//   (1 line/wave — the proven-minimal poll traffic).
//   NEW: h slots are write-once per step (poisoned 0xFF per launch; bf16 of
//   tanh-bounded h can never be 0xFFFF so dword==POISON <=> unwritten).
//   Consumer ISSUES its 16 h dword-loads BEFORE the counter spin (loads stay
//   in flight, waitcnt only at first use), validates them by poison-compare
//   after detect (pure VALU, no extra loads). Valid -> the post-detect h-load
//   hop (~0.3us) vanishes. Any poison -> single reload (guaranteed valid by
//   the drain->RMW ordering) = r10 path, nothing lost.
//   grid = 256 blocks (8 grp x 32 col) x 256 thr (4 waves), reg-resident W,
//   LDS K-partial reduce, out f32 store off the critical path.

#define TT 256
#define BB 128
#define DD 512
#define HH 512
#define KK 1024
#define NBLK 256
#define POISON 0xFFFFFFFFu

typedef __bf16 bf16x8 __attribute__((ext_vector_type(8)));
typedef float f32x4 __attribute__((ext_vector_type(4)));
typedef unsigned short u16x8 __attribute__((ext_vector_type(8)));

__device__ __forceinline__ unsigned short f2bf(float f) {
  unsigned b = __builtin_bit_cast(unsigned, f);
  return (unsigned short)((b + 0x7fffu + ((b >> 16) & 1u)) >> 16);
}
__device__ __forceinline__ float fexp(float x) {
  return __builtin_amdgcn_exp2f(x * 1.4426950408889634f);
}
__device__ __forceinline__ float fsig(float x) {
  return __builtin_amdgcn_rcpf(1.0f + fexp(-x));
}
__device__ __forceinline__ float ftanh(float x) {
  return 2.0f * fsig(2.0f * x) - 1.0f;
}

// ---- prep: X fp32 -> bf16 (RNE), 8 elems/thread ----
__global__ __launch_bounds__(256) void convert_x_kernel(const float* __restrict__ X,
                                                        unsigned short* __restrict__ Xbf) {
  size_t i = (size_t)blockIdx.x * 256 + threadIdx.x;
  const float4* src = (const float4*)X + i * 2;
  float4 v0 = src[0], v1 = src[1];
  u16x8 o;
  o[0] = f2bf(v0.x); o[1] = f2bf(v0.y); o[2] = f2bf(v0.z); o[3] = f2bf(v0.w);
  o[4] = f2bf(v1.x); o[5] = f2bf(v1.y); o[6] = f2bf(v1.z); o[7] = f2bf(v1.w);
  ((u16x8*)Xbf)[i] = o;
}

// ---- prep: build WT[g][k] bf16, g = q*512 + j; k<512 from Wq_x[k][j], else Wq_h[k-512][j].
__global__ __launch_bounds__(256) void build_wt_kernel(
    const float* __restrict__ Wax, const float* __restrict__ Wix,
    const float* __restrict__ Wfx, const float* __restrict__ Wox,
    const float* __restrict__ Wah, const float* __restrict__ Wih,
    const float* __restrict__ Wfh, const float* __restrict__ Woh,
    unsigned short* __restrict__ WT) {
  __shared__ float tile[64][65];
  int bid = blockIdx.x;           // q*128 + jt*16 + kt
  int q  = bid >> 7;
  int jt = (bid >> 4) & 7;
  int kt = bid & 15;
  const float* Wx[4] = {Wax, Wix, Wfx, Wox};
  const float* Wh[4] = {Wah, Wih, Wfh, Woh};
  const float* src = (kt < 8) ? Wx[q] : Wh[q];
  int k0 = (kt & 7) * 64;
  int j0 = jt * 64;
  int tid = threadIdx.x;
#pragma unroll
  for (int e = 0; e < 16; ++e) {
    int lin = e * 256 + tid;
    int kk = lin >> 6, jj = lin & 63;
    tile[kk][jj] = src[(size_t)(k0 + kk) * HH + j0 + jj];
  }
  __syncthreads();
#pragma unroll
  for (int e = 0; e < 16; ++e) {
    int lin = e * 256 + tid;
    int jj = lin >> 6, kk = lin & 63;
    WT[(size_t)(q * HH + j0 + jj) * KK + kt * 64 + kk] = f2bf(tile[kk][jj]);
  }
}

// ---- main persistent recurrence kernel ----
__global__ __launch_bounds__(256, 1) void lstm_main(
    const unsigned short* __restrict__ Xbf,
    const unsigned short* __restrict__ WT,
    const float* __restrict__ ba, const float* __restrict__ bi,
    const float* __restrict__ bfg, const float* __restrict__ bo,
    unsigned* __restrict__ hbq,     // [TT][8 grp][32 blk][16 row][8 colpair] u32
    float* __restrict__ out,
    unsigned* __restrict__ cnt) {   // [8 grp][256 t] x 16-u32 (64B) pad
  const int tid  = threadIdx.x;
  const int bid  = blockIdx.x;
  const int lane = tid & 63;
  const int wave = tid >> 6;
  const int rb = bid >> 5;            // 0..7  (16 batch rows) — recurrence group
  const int cb = bid & 31;            // 0..31 (16 hidden units)
  const int l15 = lane & 15;
  const int lk8 = (lane >> 4) * 8;    // k offset within a 32-chunk
  const int rbase = rb * 16;
  const int colg = cb * 16 + l15;     // hidden index for B-fragments
  const int wk = wave * 128;          // this wave's K-slice base (within each half)

  // ---- preload W fragments (constant across all timesteps) ----
  bf16x8 wf[4][8];
#pragma unroll
  for (int g = 0; g < 4; ++g) {
    const unsigned short* wg = WT + (size_t)(g * HH + colg) * KK + lk8;
#pragma unroll
    for (int c = 0; c < 8; ++c) {
      int kb = (c < 4) ? (wk + c * 32) : (DD + wk + (c - 4) * 32);
      wf[g][c] = *(const bf16x8*)(wg + kb);
    }
  }

  // per-thread output element (reduce phase): row = tid>>4, col = tid&15
  const int el_row = tid >> 4;
  const int el_col = tid & 15;
  const int el_colg = cb * 16 + el_col;
  const int el_rowg = rbase + el_row;
  const float b0 = ba[el_colg], b1 = bi[el_colg], b2 = bfg[el_colg], b3 = bo[el_colg];
  const int lsrc = (el_row >> 2) * 16 + el_col;  // source lane in C-fragment
  const int rsrc = el_row & 3;                   // source reg in C-fragment

  const unsigned short* xbase = Xbf + (size_t)(rbase + l15) * DD + wk + lk8;
  const size_t ostore_el = (size_t)el_rowg * HH + el_colg;

  // h exchange: write-once per-step slots (u32 = 2 packed bf16), group plane
  // 4096 u32/step, step slice 32768 u32. Block-exclusive 512B sub-slices.
  unsigned hload_off[4];
#pragma unroll
  for (int c = 0; c < 4; ++c) {
    int j0 = wk + c * 32 + lk8;
    hload_off[c] = (unsigned)((j0 >> 4) * 128 + l15 * 8 + ((j0 & 15) >> 1));
  }
  const unsigned hstore_off = (unsigned)(cb * 128 + el_row * 8 + (el_col >> 1));
  unsigned* hgrp = hbq + (size_t)rb * 4096;

  __shared__ f32x4 part[2][4][4][64];   // [buf][wave][gate][lane]

  float s_c = 0.f;   // cell state for this thread's element

  for (int t = 0; t < TT; ++t) {
    // ---- x part (no cross-block dependency; overlaps detect wait) ----
    const unsigned short* xt = xbase + (size_t)t * BB * DD;
    bf16x8 ax0 = *(const bf16x8*)(xt);
    bf16x8 ax1 = *(const bf16x8*)(xt + 32);
    bf16x8 ax2 = *(const bf16x8*)(xt + 64);
    bf16x8 ax3 = *(const bf16x8*)(xt + 96);

    f32x4 acc[4];
#pragma unroll
    for (int g = 0; g < 4; ++g) {
      f32x4 z = {0.f, 0.f, 0.f, 0.f};
      acc[g] = __builtin_amdgcn_mfma_f32_16x16x32_bf16(ax0, wf[g][0], z, 0, 0, 0);
      acc[g] = __builtin_amdgcn_mfma_f32_16x16x32_bf16(ax1, wf[g][1], acc[g], 0, 0, 0);
      acc[g] = __builtin_amdgcn_mfma_f32_16x16x32_bf16(ax2, wf[g][2], acc[g], 0, 0, 0);
      acc[g] = __builtin_amdgcn_mfma_f32_16x16x32_bf16(ax3, wf[g][3], acc[g], 0, 0, 0);
    }

    if (t > 0) {
      const unsigned* hp = hgrp + (size_t)(t - 1) * 32768;
      const unsigned* p0 = hp + hload_off[0];
      const unsigned* p1 = hp + hload_off[1];
      const unsigned* p2 = hp + hload_off[2];
      const unsigned* p3 = hp + hload_off[3];

      // ---- SPECULATIVE h loads: issued BEFORE detect, stay in flight ----
      uint4 q0, q1, q2, q3;
      q0.x = __hip_atomic_load(p0 + 0, __ATOMIC_RELAXED, __HIP_MEMORY_SCOPE_AGENT);
      q0.y = __hip_atomic_load(p0 + 1, __ATOMIC_RELAXED, __HIP_MEMORY_SCOPE_AGENT);
      q0.z = __hip_atomic_load(p0 + 2, __ATOMIC_RELAXED, __HIP_MEMORY_SCOPE_AGENT);
      q0.w = __hip_atomic_load(p0 + 3, __ATOMIC_RELAXED, __HIP_MEMORY_SCOPE_AGENT);
      q1.x = __hip_atomic_load(p1 + 0, __ATOMIC_RELAXED, __HIP_MEMORY_SCOPE_AGENT);
      q1.y = __hip_atomic_load(p1 + 1, __ATOMIC_RELAXED, __HIP_MEMORY_SCOPE_AGENT);
      q1.z = __hip_atomic_load(p1 + 2, __ATOMIC_RELAXED, __HIP_MEMORY_SCOPE_AGENT);
      q1.w = __hip_atomic_load(p1 + 3, __ATOMIC_RELAXED, __HIP_MEMORY_SCOPE_AGENT);
      q2.x = __hip_atomic_load(p2 + 0, __ATOMIC_RELAXED, __HIP_MEMORY_SCOPE_AGENT);
      q2.y = __hip_atomic_load(p2 + 1, __ATOMIC_RELAXED, __HIP_MEMORY_SCOPE_AGENT);
      q2.z = __hip_atomic_load(p2 + 2, __ATOMIC_RELAXED, __HIP_MEMORY_SCOPE_AGENT);
      q2.w = __hip_atomic_load(p2 + 3, __ATOMIC_RELAXED, __HIP_MEMORY_SCOPE_AGENT);
      q3.x = __hip_atomic_load(p3 + 0, __ATOMIC_RELAXED, __HIP_MEMORY_SCOPE_AGENT);
      q3.y = __hip_atomic_load(p3 + 1, __ATOMIC_RELAXED, __HIP_MEMORY_SCOPE_AGENT);
      q3.z = __hip_atomic_load(p3 + 2, __ATOMIC_RELAXED, __HIP_MEMORY_SCOPE_AGENT);
      q3.w = __hip_atomic_load(p3 + 3, __ATOMIC_RELAXED, __HIP_MEMORY_SCOPE_AGENT);

      // ---- detect: spin on aggregate counter (1 line/wave — minimal traffic) ----
      const unsigned* cptr = cnt + (size_t)(rb * TT + (t - 1)) * 16;
      unsigned v = __hip_atomic_load(cptr, __ATOMIC_RELAXED, __HIP_MEMORY_SCOPE_AGENT);
      while (v < 32u) {
        __builtin_amdgcn_s_sleep(1);
        v = __hip_atomic_load(cptr, __ATOMIC_RELAXED, __HIP_MEMORY_SCOPE_AGENT);
      }

      // ---- validate speculative data (VALU only); reload once on any poison ----
      unsigned ok = 1u;
      ok &= (q0.x != POISON) & (q0.y != POISON) & (q0.z != POISON) & (q0.w != POISON);
      ok &= (q1.x != POISON) & (q1.y != POISON) & (q1.z != POISON) & (q1.w != POISON);
      ok &= (q2.x != POISON) & (q2.y != POISON) & (q2.z != POISON) & (q2.w != POISON);
      ok &= (q3.x != POISON) & (q3.y != POISON) & (q3.z != POISON) & (q3.w != POISON);
      if (!__all(ok != 0u)) {
        // guaranteed valid now: drain->RMW ordering means counter==32 implies
        // all h stores are globally visible
        q0.x = __hip_atomic_load(p0 + 0, __ATOMIC_RELAXED, __HIP_MEMORY_SCOPE_AGENT);
        q0.y = __hip_atomic_load(p0 + 1, __ATOMIC_RELAXED, __HIP_MEMORY_SCOPE_AGENT);
        q0.z = __hip_atomic_load(p0 + 2, __ATOMIC_RELAXED, __HIP_MEMORY_SCOPE_AGENT);
        q0.w = __hip_atomic_load(p0 + 3, __ATOMIC_RELAXED, __HIP_MEMORY_SCOPE_AGENT);
        q1.x = __hip_atomic_load(p1 + 0, __ATOMIC_RELAXED, __HIP_MEMORY_SCOPE_AGENT);
        q1.y = __hip_atomic_load(p1 + 1, __ATOMIC_RELAXED, __HIP_MEMORY_SCOPE_AGENT);
        q1.z = __hip_atomic_load(p1 + 2, __ATOMIC_RELAXED, __HIP_MEMORY_SCOPE_AGENT);
        q1.w = __hip_atomic_load(p1 + 3, __ATOMIC_RELAXED, __HIP_MEMORY_SCOPE_AGENT);
        q2.x = __hip_atomic_load(p2 + 0, __ATOMIC_RELAXED, __HIP_MEMORY_SCOPE_AGENT);
        q2.y = __hip_atomic_load(p2 + 1, __ATOMIC_RELAXED, __HIP_MEMORY_SCOPE_AGENT);
        q2.z = __hip_atomic_load(p2 + 2, __ATOMIC_RELAXED, __HIP_MEMORY_SCOPE_AGENT);
        q2.w = __hip_atomic_load(p2 + 3, __ATOMIC_RELAXED, __HIP_MEMORY_SCOPE_AGENT);
        q3.x = __hip_atomic_load(p3 + 0, __ATOMIC_RELAXED, __HIP_MEMORY_SCOPE_AGENT);
        q3.y = __hip_atomic_load(p3 + 1, __ATOMIC_RELAXED, __HIP_MEMORY_SCOPE_AGENT);
        q3.z = __hip_atomic_load(p3 + 2, __ATOMIC_RELAXED, __HIP_MEMORY_SCOPE_AGENT);
        q3.w = __hip_atomic_load(p3 + 3, __ATOMIC_RELAXED, __HIP_MEMORY_SCOPE_AGENT);
      }

      bf16x8 hf0 = __builtin_bit_cast(bf16x8, q0);
      bf16x8 hf1 = __builtin_bit_cast(bf16x8, q1);
      bf16x8 hf2 = __builtin_bit_cast(bf16x8, q2);
      bf16x8 hf3 = __builtin_bit_cast(bf16x8, q3);

#pragma unroll
      for (int g = 0; g < 4; ++g) {
        acc[g] = __builtin_amdgcn_mfma_f32_16x16x32_bf16(hf0, wf[g][4], acc[g], 0, 0, 0);
        acc[g] = __builtin_amdgcn_mfma_f32_16x16x32_bf16(hf1, wf[g][5], acc[g], 0, 0, 0);
        acc[g] = __builtin_amdgcn_mfma_f32_16x16x32_bf16(hf2, wf[g][6], acc[g], 0, 0, 0);
        acc[g] = __builtin_amdgcn_mfma_f32_16x16x32_bf16(hf3, wf[g][7], acc[g], 0, 0, 0);
      }
    }

    // ---- K-partials to LDS (parity double-buffer) ----
    const int pb = t & 1;
#pragma unroll
    for (int g = 0; g < 4; ++g) part[pb][wave][g][lane] = acc[g];
    __syncthreads();

    // ---- reduce over 4 waves + gates (1 element/thread) ----
    float g0 = b0, g1 = b1, g2 = b2, g3 = b3;
#pragma unroll
    for (int w = 0; w < 4; ++w) {
      g0 += ((const float*)&part[pb][w][0][lsrc])[rsrc];
      g1 += ((const float*)&part[pb][w][1][lsrc])[rsrc];
      g2 += ((const float*)&part[pb][w][2][lsrc])[rsrc];
      g3 += ((const float*)&part[pb][w][3][lsrc])[rsrc];
    }
    float av = ftanh(g0);
    float iv = fsig(g1);
    float fv = fsig(g2);
    float ov = fsig(g3);
    s_c = av * iv + s_c * fv;
    float hv = ftanh(s_c) * ov;

    if (t < TT - 1) {
      // ---- publish h: pack 2 bf16/u32, sc1 store to write-once step slot ----
      unsigned mybf = (unsigned)f2bf(hv);
      unsigned nxbf = (unsigned)__shfl_down((int)mybf, 1);
      if ((tid & 1) == 0) {
        unsigned pack = mybf | (nxbf << 16);
        unsigned* dst = hgrp + (size_t)t * 32768 + hstore_off;
        __hip_atomic_store(dst, pack, __ATOMIC_RELAXED, __HIP_MEMORY_SCOPE_AGENT);
      }
      // drain all waves' h stores (compiler emits vmcnt(0) before s_barrier),
      // then ONE aggregate RMW per block (only last-arrival latency matters)
      __syncthreads();
      if (tid == 0)
        __hip_atomic_fetch_add(cnt + (size_t)(rb * TT + t) * 16, 1u,
                               __ATOMIC_RELAXED, __HIP_MEMORY_SCOPE_AGENT);
    }

    // ---- out store AFTER flag (drains lazily under the next step) ----
    out[(size_t)t * BB * HH + ostore_el] = hv;

    // keep h-part W fragments register-resident across iterations
#pragma unroll
    for (int g = 0; g < 4; ++g)
#pragma unroll
      for (int c = 4; c < 8; ++c)
        asm volatile("" : "+v"(wf[g][c]));
  }
}

extern "C" void kernel_launch(void* const* d_in, const int* in_sizes, int n_in,
                              void* d_out, int out_size, void* d_ws, size_t ws_size,
                              hipStream_t stream) {
  const float* X   = (const float*)d_in[0];
  const float* Wax = (const float*)d_in[1];
  const float* Wix = (const float*)d_in[2];
  const float* Wfx = (const float*)d_in[3];
  const float* Wox = (const float*)d_in[4];
  const float* Wah = (const float*)d_in[5];
  const float* Wih = (const float*)d_in[6];
  const float* Wfh = (const float*)d_in[7];
  const float* Woh = (const float*)d_in[8];
  const float* ba  = (const float*)d_in[9];
  const float* bi  = (const float*)d_in[10];
  const float* bf  = (const float*)d_in[11];
  const float* bo  = (const float*)d_in[12];
  float* out = (float*)d_out;

  char* ws = (char*)d_ws;
  unsigned short* Xbf = (unsigned short*)ws;                   // 33,554,432 B
  unsigned short* WT  = (unsigned short*)(ws + 33554432);      //  4,194,304 B
  unsigned* hbq = (unsigned*)(ws + 33554432 + 4194304);        // 33,423,360 B (255 steps x 128KB)
  unsigned* cnt = (unsigned*)(ws + 33554432 + 4194304 + 33423360);  // 131,072 B

  // poison h slots (dword 0xFFFFFFFF == unwritten) + zero counters each launch
  hipMemsetAsync(hbq, 0xFF, (size_t)(TT - 1) * 32768 * 4, stream);
  hipMemsetAsync(cnt, 0, 131072, stream);

  convert_x_kernel<<<8192, 256, 0, stream>>>(X, Xbf);
  build_wt_kernel<<<512, 256, 0, stream>>>(Wax, Wix, Wfx, Wox, Wah, Wih, Wfh, Woh, WT);
  lstm_main<<<NBLK, 256, 0, stream>>>(Xbf, WT, ba, bi, bf, bo, hbq, out, cnt);
}

// Round 16
// 644.072 us; speedup vs baseline: 1.4558x; 1.4558x over previous
//
#include <hip/hip_runtime.h>

// LSTM T=256, B=128, D=512, H=512 — FINAL (= round 10, best measured: 644us).
//   Converged design after 15 rounds. Latency-bound on the T=256 sequential
//   dependency; all structural alternatives measured worse:
//     r3 781 / r5 830 / r7 795 / r9 887 / r10 644 / r11 857 / r12 1112 /
//     r13 665 / r14 884 / r15 938; r6/r8 (XCD-placement sync) deadlocked.
//   grid = 256 blocks (8 row-groups x 32 col-blocks), 256 threads (4 waves).
//   Block tile: 16 rows x 16 hidden (4 gates); waves K-split (k in
//   [w*128,(w+1)*128) of x-half AND h-half); W fragments register-resident;
//   LDS K-partial reduce.
//   Sync per step (group = 32 blocks): publish h (block-exclusive 512B bf16
//   slices, packed u32 sc1 stores) -> __syncthreads (drains all waves' stores
//   via compiler vmcnt(0)) -> tid0 fetch_add on 64B-padded per-(group,t)
//   counter -> consumers poll counter==32 (all lanes same addr = 1 line/wave,
//   the proven-minimal poll traffic) -> h loads -> MFMAs.
//   out f32 stores AFTER the flag (drain lazily). No placement assumptions,
//   no threadfence, deadlock-impossible (wait only on co-resident group).

#define TT 256
#define BB 128
#define DD 512
#define HH 512
#define KK 1024
#define NBLK 256

typedef __bf16 bf16x8 __attribute__((ext_vector_type(8)));
typedef float f32x4 __attribute__((ext_vector_type(4)));
typedef unsigned short u16x8 __attribute__((ext_vector_type(8)));
typedef unsigned long long u64;

union h128 { u64 q[2]; bf16x8 v; };

__device__ __forceinline__ unsigned short f2bf(float f) {
  unsigned b = __builtin_bit_cast(unsigned, f);
  return (unsigned short)((b + 0x7fffu + ((b >> 16) & 1u)) >> 16);
}
__device__ __forceinline__ float fexp(float x) {
  return __builtin_amdgcn_exp2f(x * 1.4426950408889634f);
}
__device__ __forceinline__ float fsig(float x) {
  return __builtin_amdgcn_rcpf(1.0f + fexp(-x));
}
__device__ __forceinline__ float ftanh(float x) {
  return 2.0f * fsig(2.0f * x) - 1.0f;
}

// ---- prep: X fp32 -> bf16 (RNE), 8 elems/thread ----
__global__ __launch_bounds__(256) void convert_x_kernel(const float* __restrict__ X,
                                                        unsigned short* __restrict__ Xbf) {
  size_t i = (size_t)blockIdx.x * 256 + threadIdx.x;
  const float4* src = (const float4*)X + i * 2;
  float4 v0 = src[0], v1 = src[1];
  u16x8 o;
  o[0] = f2bf(v0.x); o[1] = f2bf(v0.y); o[2] = f2bf(v0.z); o[3] = f2bf(v0.w);
  o[4] = f2bf(v1.x); o[5] = f2bf(v1.y); o[6] = f2bf(v1.z); o[7] = f2bf(v1.w);
  ((u16x8*)Xbf)[i] = o;
}

// ---- prep: build WT[g][k] bf16, g = q*512 + j; k<512 from Wq_x[k][j], else Wq_h[k-512][j].
__global__ __launch_bounds__(256) void build_wt_kernel(
    const float* __restrict__ Wax, const float* __restrict__ Wix,
    const float* __restrict__ Wfx, const float* __restrict__ Wox,
    const float* __restrict__ Wah, const float* __restrict__ Wih,
    const float* __restrict__ Wfh, const float* __restrict__ Woh,
    unsigned short* __restrict__ WT) {
  __shared__ float tile[64][65];
  int bid = blockIdx.x;           // q*128 + jt*16 + kt
  int q  = bid >> 7;
  int jt = (bid >> 4) & 7;
  int kt = bid & 15;
  const float* Wx[4] = {Wax, Wix, Wfx, Wox};
  const float* Wh[4] = {Wah, Wih, Wfh, Woh};
  const float* src = (kt < 8) ? Wx[q] : Wh[q];
  int k0 = (kt & 7) * 64;
  int j0 = jt * 64;
  int tid = threadIdx.x;
#pragma unroll
  for (int e = 0; e < 16; ++e) {
    int lin = e * 256 + tid;
    int kk = lin >> 6, jj = lin & 63;
    tile[kk][jj] = src[(size_t)(k0 + kk) * HH + j0 + jj];
  }
  __syncthreads();
#pragma unroll
  for (int e = 0; e < 16; ++e) {
    int lin = e * 256 + tid;
    int jj = lin >> 6, kk = lin & 63;
    WT[(size_t)(q * HH + j0 + jj) * KK + kt * 64 + kk] = f2bf(tile[kk][jj]);
  }
}

// ---- main persistent recurrence kernel ----
__global__ __launch_bounds__(256, 1) void lstm_main(
    const unsigned short* __restrict__ Xbf,
    const unsigned short* __restrict__ WT,
    const float* __restrict__ ba, const float* __restrict__ bi,
    const float* __restrict__ bfg, const float* __restrict__ bo,
    unsigned short* __restrict__ hbq,   // [8 grp][2 plane][32 blk][16 row][16 col] bf16
    float* __restrict__ out,
    unsigned* __restrict__ cnt) {       // [8 grp][256 t] x 16-u32 (64B) pad
  const int tid  = threadIdx.x;
  const int bid  = blockIdx.x;
  const int lane = tid & 63;
  const int wave = tid >> 6;
  const int rb = bid >> 5;            // 0..7  (16 batch rows) — recurrence group
  const int cb = bid & 31;            // 0..31 (16 hidden units)
  const int l15 = lane & 15;
  const int lk8 = (lane >> 4) * 8;    // k offset within a 32-chunk
  const int rbase = rb * 16;
  const int colg = cb * 16 + l15;     // hidden index for B-fragments
  const int wk = wave * 128;          // this wave's K-slice base (within each half)

  // ---- preload W fragments (constant across all timesteps) ----
  bf16x8 wf[4][8];
#pragma unroll
  for (int g = 0; g < 4; ++g) {
    const unsigned short* wg = WT + (size_t)(g * HH + colg) * KK + lk8;
#pragma unroll
    for (int c = 0; c < 8; ++c) {
      int kb = (c < 4) ? (wk + c * 32) : (DD + wk + (c - 4) * 32);
      wf[g][c] = *(const bf16x8*)(wg + kb);
    }
  }

  // per-thread output element (reduce phase): row = tid>>4, col = tid&15
  const int el_row = tid >> 4;
  const int el_col = tid & 15;
  const int el_colg = cb * 16 + el_col;
  const int el_rowg = rbase + el_row;
  const float b0 = ba[el_colg], b1 = bi[el_colg], b2 = bfg[el_colg], b3 = bo[el_colg];
  const int lsrc = (el_row >> 2) * 16 + el_col;  // source lane in C-fragment
  const int rsrc = el_row & 3;                   // source reg in C-fragment

  const unsigned short* xbase = Xbf + (size_t)(rbase + l15) * DD + wk + lk8;
  const size_t ostore_el = (size_t)el_rowg * HH + el_colg;

  // h exchange: group-local, block-exclusive 512B slices.
  // element index within a plane: blk*256 + row*16 + col; plane = 8192 elems.
  unsigned short* hgrp = hbq + (size_t)rb * (2 * 8192);
  // consumer: per chunk c, hidden cols j0 = wk + c*32 + lk8 (8 contiguous,
  // within one block slice since j0 % 16 in {0,8})
  size_t hload_off[4];
#pragma unroll
  for (int c = 0; c < 4; ++c) {
    int j0 = wk + c * 32 + lk8;
    hload_off[c] = (size_t)(j0 >> 4) * 256 + (size_t)l15 * 16 + (j0 & 15);
  }
  // producer: this thread's element -> slice cb, row el_row, col el_col
  const size_t hstore_off = (size_t)cb * 256 + (size_t)el_row * 16 + el_col;

  __shared__ f32x4 part[2][4][4][64];   // [buf][wave][gate][lane]

  float s_c = 0.f;   // cell state for this thread's element

  for (int t = 0; t < TT; ++t) {
    // ---- x part (no cross-block dependency; overlaps poll wait) ----
    const unsigned short* xt = xbase + (size_t)t * BB * DD;
    bf16x8 ax0 = *(const bf16x8*)(xt);
    bf16x8 ax1 = *(const bf16x8*)(xt + 32);
    bf16x8 ax2 = *(const bf16x8*)(xt + 64);
    bf16x8 ax3 = *(const bf16x8*)(xt + 96);

    f32x4 acc[4];
#pragma unroll
    for (int g = 0; g < 4; ++g) {
      f32x4 z = {0.f, 0.f, 0.f, 0.f};
      acc[g] = __builtin_amdgcn_mfma_f32_16x16x32_bf16(ax0, wf[g][0], z, 0, 0, 0);
      acc[g] = __builtin_amdgcn_mfma_f32_16x16x32_bf16(ax1, wf[g][1], acc[g], 0, 0, 0);
      acc[g] = __builtin_amdgcn_mfma_f32_16x16x32_bf16(ax2, wf[g][2], acc[g], 0, 0, 0);
      acc[g] = __builtin_amdgcn_mfma_f32_16x16x32_bf16(ax3, wf[g][3], acc[g], 0, 0, 0);
    }

    if (t > 0) {
      // ---- every wave polls the group counter (all lanes same addr = 1 req) ----
      const unsigned* cptr = cnt + (size_t)(rb * TT + (t - 1)) * 16;
      unsigned v = __hip_atomic_load(cptr, __ATOMIC_RELAXED, __HIP_MEMORY_SCOPE_AGENT);
      while (v < 32u) {
        __builtin_amdgcn_s_sleep(1);
        v = __hip_atomic_load(cptr, __ATOMIC_RELAXED, __HIP_MEMORY_SCOPE_AGENT);
      }
      asm volatile("" ::: "memory");  // keep h loads below the poll

      // ---- h loads (8 parallel u64 sc1 loads from block-exclusive slices) ----
      const unsigned short* hp = hgrp + (size_t)(((t & 1) ^ 1)) * 8192;
      h128 u0, u1, u2, u3;
      const u64* q0 = (const u64*)(hp + hload_off[0]);
      const u64* q1 = (const u64*)(hp + hload_off[1]);
      const u64* q2 = (const u64*)(hp + hload_off[2]);
      const u64* q3 = (const u64*)(hp + hload_off[3]);
      u0.q[0] = __hip_atomic_load(q0,     __ATOMIC_RELAXED, __HIP_MEMORY_SCOPE_AGENT);
      u0.q[1] = __hip_atomic_load(q0 + 1, __ATOMIC_RELAXED, __HIP_MEMORY_SCOPE_AGENT);
      u1.q[0] = __hip_atomic_load(q1,     __ATOMIC_RELAXED, __HIP_MEMORY_SCOPE_AGENT);
      u1.q[1] = __hip_atomic_load(q1 + 1, __ATOMIC_RELAXED, __HIP_MEMORY_SCOPE_AGENT);
      u2.q[0] = __hip_atomic_load(q2,     __ATOMIC_RELAXED, __HIP_MEMORY_SCOPE_AGENT);
      u2.q[1] = __hip_atomic_load(q2 + 1, __ATOMIC_RELAXED, __HIP_MEMORY_SCOPE_AGENT);
      u3.q[0] = __hip_atomic_load(q3,     __ATOMIC_RELAXED, __HIP_MEMORY_SCOPE_AGENT);
      u3.q[1] = __hip_atomic_load(q3 + 1, __ATOMIC_RELAXED, __HIP_MEMORY_SCOPE_AGENT);

#pragma unroll
      for (int g = 0; g < 4; ++g) {
        acc[g] = __builtin_amdgcn_mfma_f32_16x16x32_bf16(u0.v, wf[g][4], acc[g], 0, 0, 0);
        acc[g] = __builtin_amdgcn_mfma_f32_16x16x32_bf16(u1.v, wf[g][5], acc[g], 0, 0, 0);
        acc[g] = __builtin_amdgcn_mfma_f32_16x16x32_bf16(u2.v, wf[g][6], acc[g], 0, 0, 0);
        acc[g] = __builtin_amdgcn_mfma_f32_16x16x32_bf16(u3.v, wf[g][7], acc[g], 0, 0, 0);
      }
    }

    // ---- K-partials to LDS (parity double-buffer) ----
    const int pb = t & 1;
#pragma unroll
    for (int g = 0; g < 4; ++g) part[pb][wave][g][lane] = acc[g];
    __syncthreads();

    // ---- reduce over 4 waves + gates (1 element/thread) ----
    float g0 = b0, g1 = b1, g2 = b2, g3 = b3;
#pragma unroll
    for (int w = 0; w < 4; ++w) {
      g0 += ((const float*)&part[pb][w][0][lsrc])[rsrc];
      g1 += ((const float*)&part[pb][w][1][lsrc])[rsrc];
      g2 += ((const float*)&part[pb][w][2][lsrc])[rsrc];
      g3 += ((const float*)&part[pb][w][3][lsrc])[rsrc];
    }
    float av = ftanh(g0);
    float iv = fsig(g1);
    float fv = fsig(g2);
    float ov = fsig(g3);
    s_c = av * iv + s_c * fv;
    float hv = ftanh(s_c) * ov;

    if (t < TT - 1) {
      // ---- publish h: pack 2 bf16/u32, sc1 store to block-exclusive slice ----
      unsigned mybf = (unsigned)f2bf(hv);
      unsigned nxbf = (unsigned)__shfl_down((int)mybf, 1);
      if ((tid & 1) == 0) {
        unsigned pack = mybf | (nxbf << 16);
        unsigned* dst = (unsigned*)(hgrp + (size_t)pb * 8192 + hstore_off);
        __hip_atomic_store(dst, pack, __ATOMIC_RELAXED, __HIP_MEMORY_SCOPE_AGENT);
      }
      // drain all waves' h stores (compiler emits vmcnt(0) before s_barrier),
      // then ONE aggregate RMW per block (only last-arrival latency matters)
      __syncthreads();
      if (tid == 0)
        __hip_atomic_fetch_add(cnt + (size_t)(rb * TT + t) * 16, 1u,
                               __ATOMIC_RELAXED, __HIP_MEMORY_SCOPE_AGENT);
    }

    // ---- out store AFTER flag (drains lazily under the next step) ----
    out[(size_t)t * BB * HH + ostore_el] = hv;

    // keep h-part W fragments register-resident across iterations
#pragma unroll
    for (int g = 0; g < 4; ++g)
#pragma unroll
      for (int c = 4; c < 8; ++c)
        asm volatile("" : "+v"(wf[g][c]));
  }
}

extern "C" void kernel_launch(void* const* d_in, const int* in_sizes, int n_in,
                              void* d_out, int out_size, void* d_ws, size_t ws_size,
                              hipStream_t stream) {
  const float* X   = (const float*)d_in[0];
  const float* Wax = (const float*)d_in[1];
  const float* Wix = (const float*)d_in[2];
  const float* Wfx = (const float*)d_in[3];
  const float* Wox = (const float*)d_in[4];
  const float* Wah = (const float*)d_in[5];
  const float* Wih = (const float*)d_in[6];
  const float* Wfh = (const float*)d_in[7];
  const float* Woh = (const float*)d_in[8];
  const float* ba  = (const float*)d_in[9];
  const float* bi  = (const float*)d_in[10];
  const float* bf  = (const float*)d_in[11];
  const float* bo  = (const float*)d_in[12];
  float* out = (float*)d_out;

  char* ws = (char*)d_ws;
  unsigned short* Xbf = (unsigned short*)ws;                        // 33,554,432 B
  unsigned short* WT  = (unsigned short*)(ws + 33554432);           //  4,194,304 B
  unsigned short* hbq = (unsigned short*)(ws + 33554432 + 4194304); //    262,144 B
  unsigned* cnt = (unsigned*)(ws + 33554432 + 4194304 + 262144);    //    131,072 B

  // zero counters every launch (hbq needs no init: t=0 skips h reads; every
  // plane is written before read; replay-stale values are identical anyway)
  hipMemsetAsync(cnt, 0, 131072, stream);

  convert_x_kernel<<<8192, 256, 0, stream>>>(X, Xbf);
  build_wt_kernel<<<512, 256, 0, stream>>>(Wax, Wix, Wfx, Wox, Wah, Wih, Wfh, Woh, WT);
  lstm_main<<<NBLK, 256, 0, stream>>>(Xbf, WT, ba, bi, bf, bo, hbq, out, cnt);
}